// Round 3
// baseline (1750.415 us; speedup 1.0000x reference)
//
#include <hip/hip_runtime.h>

#define N_NODES 1000000
#define D 64
#define H 128

// ---------------------------------------------------------------------------
// Detect whether edge_index arrived as int32 or int64.
// Indices are < 1e6 (< 2^20), so for int64 data every odd u32 word (the high
// half, little-endian) is zero. For int32 data the odd words are real indices
// (uniform in [0,1e6)) — P(2048 consecutive all zero) ~ 0.
// flag = 1 -> int32, flag = 0 -> int64.
// ---------------------------------------------------------------------------
__global__ __launch_bounds__(256) void detect_kernel(const unsigned int* __restrict__ e,
                                                     int* __restrict__ flag) {
    __shared__ int any_nz;
    if (threadIdx.x == 0) any_nz = 0;
    __syncthreads();
    int nz = 0;
    for (int k = threadIdx.x; k < 2048; k += 256) {
        if (e[2 * k + 1] != 0u) nz = 1;
    }
    if (nz) atomicOr(&any_nz, 1);
    __syncthreads();
    if (threadIdx.x == 0) *flag = any_nz;
}

// ---------------------------------------------------------------------------
// One-time transpose of w2 [D][H] -> w2t [H][D] so the MLP's u-update reads a
// CONTIGUOUS row per hidden unit (s_load_dwordx8 stream) instead of 64
// scattered stride-512B s_load_dword's per j (scalar-cache thrash).
// ---------------------------------------------------------------------------
__global__ __launch_bounds__(256) void transpose_w2_kernel(const float* __restrict__ w2,
                                                           float* __restrict__ w2t) {
    int idx = blockIdx.x * 256 + threadIdx.x;  // D*H = 8192 elements
    if (idx < D * H) {
        int i = idx >> 7;        // row in w2  (output dim, /H with H=128)
        int j = idx & (H - 1);   // col in w2  (hidden dim)
        w2t[j * D + i] = w2[idx];
    }
}

// ---------------------------------------------------------------------------
// Scatter-add: one wave (64 lanes) per edge; lane i handles feature i.
// msg[dst][i] += emb[src][i]  via fp32 global atomics.
// ---------------------------------------------------------------------------
__global__ __launch_bounds__(256) void scatter_kernel(const void* __restrict__ edges,
                                                      const float* __restrict__ emb,
                                                      float* __restrict__ msg,
                                                      const int* __restrict__ flag,
                                                      int E) {
    int idx  = blockIdx.x * 256 + threadIdx.x;
    int e    = idx >> 6;
    int lane = idx & 63;
    if (e >= E) return;

    long long s, d;
    if (*flag) {  // int32 layout
        const int* p = (const int*)edges;
        s = p[e];
        d = p[E + e];
    } else {      // int64 layout
        const long long* p = (const long long*)edges;
        s = p[e];
        d = p[E + e];
    }

    float v = emb[s * (long long)D + lane];
    atomicAdd(msg + d * (long long)D + lane, v);
}

// ---------------------------------------------------------------------------
// Fused MLP + residual, in place on io (io holds messages on entry, result on
// exit). One thread per node. Weights are read with wave-uniform indices so
// the compiler issues scalar (s_load) fetches on the scalar pipe; both w1 and
// w2t rows are contiguous.
//
// amdgpu_waves_per_eu(2,2): pin the allocator's occupancy TARGET to exactly
// 2 waves/EU (VGPR budget 256). __launch_bounds__(256,2) only set the
// minimum (a cap of 256) — the allocator still targeted ~7 waves/EU, chose
// 72 VGPRs, and spilled one 64-float array to scratch (seen as +250 MB
// WRITE_SIZE, VALUBusy 32%, and unchanged VGPR_Count=72 across rounds).
// The live set (m[64] + u[64] + temps ~ 150 VGPRs) must stay in registers.
//
//   h_j = relu(b1_j + sum_k m_k * w1[j,k])       (j = 0..127)
//   u_i = relu(b2_i + sum_j h_j * w2t[j,i])      (i = 0..63)
//   out = emb + u
// ---------------------------------------------------------------------------
__global__ __launch_bounds__(256)
__attribute__((amdgpu_waves_per_eu(2, 2)))
void mlp_kernel(float* io,
                const float* __restrict__ emb,
                const float* __restrict__ w1,
                const float* __restrict__ b1,
                const float* __restrict__ w2t,
                const float* __restrict__ b2) {
    int n = blockIdx.x * 256 + threadIdx.x;
    if (n >= N_NODES) return;

    float m[D];
    {
        const float4* p  = (const float4*)(io + (size_t)n * D);
        float4*       mv = (float4*)m;
#pragma unroll
        for (int c = 0; c < D / 4; ++c) mv[c] = p[c];
    }

    float u[D];
#pragma unroll
    for (int i = 0; i < D; ++i) u[i] = b2[i];

#pragma unroll 2
    for (int j = 0; j < H; ++j) {
        const float* wr = w1 + j * D;
        // 4 partial accumulators: break the 64-deep dependent FMA chain
        // (4-cyc dependent latency) into 4 independent 16-deep chains.
        float h0 = 0.0f, h1 = 0.0f, h2 = 0.0f, h3 = 0.0f;
#pragma unroll
        for (int k = 0; k < D; k += 4) {
            h0 = fmaf(m[k + 0], wr[k + 0], h0);
            h1 = fmaf(m[k + 1], wr[k + 1], h1);
            h2 = fmaf(m[k + 2], wr[k + 2], h2);
            h3 = fmaf(m[k + 3], wr[k + 3], h3);
        }
        float h = fmaxf((h0 + h1) + (h2 + h3) + b1[j], 0.0f);

        const float* wc = w2t + j * D;  // contiguous row of transposed w2
#pragma unroll
        for (int i = 0; i < D; ++i) u[i] = fmaf(h, wc[i], u[i]);
    }

    const float4* ev = (const float4*)(emb + (size_t)n * D);
    float4*       ov = (float4*)(io + (size_t)n * D);
#pragma unroll
    for (int c = 0; c < D / 4; ++c) {
        float4 e4 = ev[c];
        float4 r;
        r.x = e4.x + fmaxf(u[4 * c + 0], 0.0f);
        r.y = e4.y + fmaxf(u[4 * c + 1], 0.0f);
        r.z = e4.z + fmaxf(u[4 * c + 2], 0.0f);
        r.w = e4.w + fmaxf(u[4 * c + 3], 0.0f);
        ov[c] = r;
    }
}

extern "C" void kernel_launch(void* const* d_in, const int* in_sizes, int n_in,
                              void* d_out, int out_size, void* d_ws, size_t ws_size,
                              hipStream_t stream) {
    const void*  edges = d_in[0];
    const float* emb   = (const float*)d_in[1];
    const float* w1    = (const float*)d_in[2];
    const float* b1    = (const float*)d_in[3];
    const float* w2    = (const float*)d_in[4];
    const float* b2    = (const float*)d_in[5];
    float*       out   = (float*)d_out;

    int*   flag = (int*)d_ws;
    float* w2t  = (float*)((char*)d_ws + 256);  // 32 KB transposed w2

    const int E = in_sizes[0] / 2;  // 1,250,000 edges (element count same for i32/i64)

    // d_out doubles as the messages accumulator: zero it first.
    hipMemsetAsync(out, 0, (size_t)N_NODES * D * sizeof(float), stream);

    detect_kernel<<<1, 256, 0, stream>>>((const unsigned int*)edges, flag);
    transpose_w2_kernel<<<(D * H + 255) / 256, 256, 0, stream>>>(w2, w2t);

    // One wave per edge -> E*64 threads.
    long long sthreads = (long long)E * 64;
    int       sblocks  = (int)((sthreads + 255) / 256);
    scatter_kernel<<<sblocks, 256, 0, stream>>>(edges, emb, out, flag, E);

    int mblocks = (N_NODES + 255) / 256;
    mlp_kernel<<<mblocks, 256, 0, stream>>>(out, emb, w1, b1, w2t, b2);
}

// Round 4
// 1307.622 us; speedup vs baseline: 1.3386x; 1.3386x over previous
//
#include <hip/hip_runtime.h>

#define N_NODES 1000000
#define D 64
#define H 128

// Native 4-float vector type. The MLP state (m[16], u[16]) is declared in
// this type and indexed ONLY with compile-time constants — no (float4*) casts
// into allocas. Rounds 0-3 proved the cast-based arrays were never promoted
// by SROA (VGPR_Count stayed 72-88 regardless of waves_per_eu budget, with
// ~250-350 MB of scratch WRITE_SIZE): the reinterpret-cast view of the alloca
// blocked promotion, so the arrays lived in scratch the whole time.
typedef float f4 __attribute__((ext_vector_type(4)));

// ---------------------------------------------------------------------------
// Detect whether edge_index arrived as int32 or int64.
// Indices are < 1e6 (< 2^20), so for int64 data every odd u32 word (the high
// half, little-endian) is zero. For int32 data the odd words are real indices
// (uniform in [0,1e6)) — P(2048 consecutive all zero) ~ 0.
// flag = 1 -> int32, flag = 0 -> int64.
// ---------------------------------------------------------------------------
__global__ __launch_bounds__(256) void detect_kernel(const unsigned int* __restrict__ e,
                                                     int* __restrict__ flag) {
    __shared__ int any_nz;
    if (threadIdx.x == 0) any_nz = 0;
    __syncthreads();
    int nz = 0;
    for (int k = threadIdx.x; k < 2048; k += 256) {
        if (e[2 * k + 1] != 0u) nz = 1;
    }
    if (nz) atomicOr(&any_nz, 1);
    __syncthreads();
    if (threadIdx.x == 0) *flag = any_nz;
}

// ---------------------------------------------------------------------------
// One-time transpose of w2 [D][H] -> w2t [H][D] so the MLP's u-update reads a
// CONTIGUOUS row per hidden unit (scalar-pipe dwordx4 stream) instead of 64
// scattered stride-512B loads per j (scalar-cache thrash). This transpose
// was worth 1140->785 us on its own in round 1.
// ---------------------------------------------------------------------------
__global__ __launch_bounds__(256) void transpose_w2_kernel(const float* __restrict__ w2,
                                                           float* __restrict__ w2t) {
    int idx = blockIdx.x * 256 + threadIdx.x;  // D*H = 8192 elements
    if (idx < D * H) {
        int i = idx >> 7;        // row in w2  (output dim, /H with H=128)
        int j = idx & (H - 1);   // col in w2  (hidden dim)
        w2t[j * D + i] = w2[idx];
    }
}

// ---------------------------------------------------------------------------
// Scatter-add: one wave (64 lanes) per edge; lane i handles feature i.
// msg[dst][i] += emb[src][i]  via fp32 global atomics.
// ---------------------------------------------------------------------------
__global__ __launch_bounds__(256) void scatter_kernel(const void* __restrict__ edges,
                                                      const float* __restrict__ emb,
                                                      float* __restrict__ msg,
                                                      const int* __restrict__ flag,
                                                      int E) {
    int idx  = blockIdx.x * 256 + threadIdx.x;
    int e    = idx >> 6;
    int lane = idx & 63;
    if (e >= E) return;

    long long s, d;
    if (*flag) {  // int32 layout
        const int* p = (const int*)edges;
        s = p[e];
        d = p[E + e];
    } else {      // int64 layout
        const long long* p = (const long long*)edges;
        s = p[e];
        d = p[E + e];
    }

    float v = emb[s * (long long)D + lane];
    atomicAdd(msg + d * (long long)D + lane, v);
}

// ---------------------------------------------------------------------------
// Fused MLP + residual, in place on io (io holds messages on entry, result on
// exit). One thread per node. Weight rows are read with wave-uniform
// addresses (j is a uniform loop counter) so the compiler issues scalar
// s_load streams on the scalar pipe; both w1 and w2t rows are contiguous.
//
// State: m[16] + u[16] f4-vectors = 128 floats, all constant-indexed ->
// SROA-promotable. waves_per_eu(2,3): allocator targets 3 waves/EU = 170
// VGPR budget, enough for the ~140-reg live set with zero scratch.
//
//   h_j = relu(b1_j + sum_k m_k * w1[j,k])       (j = 0..127)
//   u_i = relu(b2_i + sum_j h_j * w2t[j,i])      (i = 0..63)
//   out = emb + u
// ---------------------------------------------------------------------------
__global__ __launch_bounds__(256)
__attribute__((amdgpu_waves_per_eu(2, 3)))
void mlp_kernel(float* __restrict__ io,
                const float* __restrict__ emb,
                const float* __restrict__ w1,
                const float* __restrict__ b1,
                const float* __restrict__ w2t,
                const float* __restrict__ b2) {
    int n = blockIdx.x * 256 + threadIdx.x;
    if (n >= N_NODES) return;

    const f4* __restrict__ mp = (const f4*)(io + (size_t)n * D);
    f4 m[D / 4];
#pragma unroll
    for (int c = 0; c < D / 4; ++c) m[c] = mp[c];

    const f4* __restrict__ b2v = (const f4*)b2;
    f4 u[D / 4];
#pragma unroll
    for (int c = 0; c < D / 4; ++c) u[c] = b2v[c];

#pragma unroll 2
    for (int j = 0; j < H; ++j) {
        const f4* __restrict__ wr = (const f4*)(w1 + j * D);
        // 4 partial sums live in the vector lanes of acc: 4 independent
        // 16-deep FMA chains instead of one 64-deep chain.
        f4 acc = (f4){0.0f, 0.0f, 0.0f, 0.0f};
#pragma unroll
        for (int c = 0; c < D / 4; ++c) acc = m[c] * wr[c] + acc;  // contracts to v_fma
        float h = (acc[0] + acc[1]) + (acc[2] + acc[3]) + b1[j];
        h = fmaxf(h, 0.0f);

        const f4* __restrict__ wc = (const f4*)(w2t + j * D);  // contiguous row
#pragma unroll
        for (int c = 0; c < D / 4; ++c) u[c] = h * wc[c] + u[c];
    }

    const f4* __restrict__ ev = (const f4*)(emb + (size_t)n * D);
    f4* __restrict__ ov = (f4*)(io + (size_t)n * D);
#pragma unroll
    for (int c = 0; c < D / 4; ++c) {
        f4 r;
        r[0] = ev[c][0] + fmaxf(u[c][0], 0.0f);
        r[1] = ev[c][1] + fmaxf(u[c][1], 0.0f);
        r[2] = ev[c][2] + fmaxf(u[c][2], 0.0f);
        r[3] = ev[c][3] + fmaxf(u[c][3], 0.0f);
        ov[c] = r;
    }
}

extern "C" void kernel_launch(void* const* d_in, const int* in_sizes, int n_in,
                              void* d_out, int out_size, void* d_ws, size_t ws_size,
                              hipStream_t stream) {
    const void*  edges = d_in[0];
    const float* emb   = (const float*)d_in[1];
    const float* w1    = (const float*)d_in[2];
    const float* b1    = (const float*)d_in[3];
    const float* w2    = (const float*)d_in[4];
    const float* b2    = (const float*)d_in[5];
    float*       out   = (float*)d_out;

    int*   flag = (int*)d_ws;
    float* w2t  = (float*)((char*)d_ws + 256);  // 32 KB transposed w2

    const int E = in_sizes[0] / 2;  // 1,250,000 edges (element count same for i32/i64)

    // d_out doubles as the messages accumulator: zero it first.
    hipMemsetAsync(out, 0, (size_t)N_NODES * D * sizeof(float), stream);

    detect_kernel<<<1, 256, 0, stream>>>((const unsigned int*)edges, flag);
    transpose_w2_kernel<<<(D * H + 255) / 256, 256, 0, stream>>>(w2, w2t);

    // One wave per edge -> E*64 threads.
    long long sthreads = (long long)E * 64;
    int       sblocks  = (int)((sthreads + 255) / 256);
    scatter_kernel<<<sblocks, 256, 0, stream>>>(edges, emb, out, flag, E);

    int mblocks = (N_NODES + 255) / 256;
    mlp_kernel<<<mblocks, 256, 0, stream>>>(out, emb, w1, b1, w2t, b2);
}